// Round 1
// baseline (2807.082 us; speedup 1.0000x reference)
//
#include <hip/hip_runtime.h>

// ---------------------------------------------------------------------------
// snnBlock: T=4 timesteps of
//   1) snn.Alpha      : dual-exp leaky integrator + subtract reset + spike
//   2) SConv2dLSTM    : 3x3 SAME conv (Cin+Cout=192 -> 4*Cout=512 gates), LSTM
//   3) BatchNormTT2d  : per-timestep BN over (B,H,W) of the *binary* spikes
// Shapes: x [4,8,64,48,48] f32, out [4,8,128,48,48] f32.
// ---------------------------------------------------------------------------

#define T_ 4
#define B_ 8
#define CIN 64
#define COUT 128
#define H_ 48
#define W_ 48
#define HW (H_ * W_)          // 2304
#define CCOMB (CIN + COUT)    // 192
#define NGATE (4 * COUT)      // 512
#define NPIX (B_ * HW)        // 18432
#define KTOT (CCOMB * 9)      // 1728

// ---- workspace layout (in 32-bit words) ----
#define LEN_SYNE (B_ * CIN * HW)    // 1179648
#define LEN_SYN2 (B_ * COUT * HW)   // 2359296
#define LEN_COMB (B_ * CCOMB * HW)  // 3538944
#define LEN_CC   (B_ * NGATE * HW)  // 9437184
#define LEN_CNT  (T_ * COUT)        // 512 (ints)

#define OFF_SYNE 0
#define OFF_SYNI (OFF_SYNE + LEN_SYNE)
#define OFF_SYN2 (OFF_SYNI + LEN_SYNE)
#define OFF_COMB (OFF_SYN2 + LEN_SYN2)
#define OFF_CNT  (OFF_COMB + LEN_COMB)
#define OFF_SPK2 (OFF_CNT + LEN_CNT)
#define OFF_CC   (OFF_SPK2 + LEN_SYN2)
#define ZERO_WORDS OFF_SPK2   // zero: syn_e, syn_i, syn2, comb, counts

// ---------------------------------------------------------------------------
__global__ __launch_bounds__(256) void zero_ws_kernel(float* __restrict__ p, int n) {
    int i = blockIdx.x * 256 + threadIdx.x;
    if (i < n) p[i] = 0.0f;
}

// ---------------------------------------------------------------------------
// Alpha neuron step over B*CIN*HW elements. Writes new spk1 into comb[:, 0:64].
__global__ __launch_bounds__(256) void alpha_step_kernel(
        const float* __restrict__ x_t,
        const float* __restrict__ p_alpha, const float* __restrict__ p_beta,
        const float* __restrict__ p_th1,
        float* __restrict__ syn_e, float* __restrict__ syn_i,
        float* __restrict__ comb) {
#pragma clang fp contract(off)
    int i = blockIdx.x * 256 + threadIdx.x;   // exact multiple: 1179648 = 4608*256
    float a = fminf(fmaxf(p_alpha[0], 1e-6f), 1.0f - 1e-6f);
    float b = fminf(fmaxf(p_beta[0],  1e-6f), 1.0f - 1e-6f);
    float la = logf(a), lb = logf(b);
    float tau = la / (lb - la);
    float th1 = p_th1[0];

    float xv = x_t[i];
    float e  = a * syn_e[i] + xv;
    float ii = b * syn_i[i] - xv;
    // map [b][c<64][p] -> comb [b][c][p] with comb channel stride CCOMB
    int bidx = i / (CIN * HW);
    int rem  = i - bidx * (CIN * HW);
    int cidx = bidx * (CCOMB * HW) + rem;
    float sp_prev = comb[cidx];
    float m1 = tau * (e + ii) - sp_prev * th1;
    float s1 = (m1 - th1) > 0.0f ? 1.0f : 0.0f;
    syn_e[i] = e;
    syn_i[i] = ii;
    comb[cidx] = s1;
}

// ---------------------------------------------------------------------------
// Gate conv: comb [B,192,48,48] * w [512,192,3,3] + bias -> cc [B,512,48,48]
// Block: 256 threads; one (batch, 8x8 spatial tile, 128-oc group).
// K-loop: 24 chunks of 8 input channels (72 k-elements each).
// Thread: 4 spatial (consecutive w) x 8 oc accumulators.
#define WPAD 129   // pad wlds row to break the k-major staging bank conflict
__global__ __launch_bounds__(256) void conv_gates_kernel(
        const float* __restrict__ comb, const float* __restrict__ w,
        const float* __restrict__ bias, float* __restrict__ cc) {
    __shared__ float ilds[8][10][10];     // [ci][row][col], halo'd 8x8 tile
    __shared__ float wlds[72][WPAD];      // [k][oc]

    const int bx   = blockIdx.x;          // 0..1151
    const int ocg  = bx & 3;              // 128-oc group
    const int tile = (bx >> 2) % 36;      // 6x6 tiles of 8x8
    const int b    = bx / 144;
    const int th0  = (tile / 6) * 8;
    const int tw0  = (tile % 6) * 8;
    const int ocBase = ocg * 128;

    const int tid = threadIdx.x;
    const int q   = tid & 15;             // 16 spatial quads
    const int qr  = q >> 1;               // row 0..7
    const int qc4 = (q & 1) * 4;          // col base 0 or 4
    const int og8 = (tid >> 4) * 8;       // oc sub-base 0..120

    float acc[4][8];
#pragma unroll
    for (int j = 0; j < 4; ++j)
#pragma unroll
        for (int o = 0; o < 8; ++o) acc[j][o] = 0.0f;

    for (int cic = 0; cic < 24; ++cic) {
        const int ciBase = cic * 8;
        const int wkBase = ciBase * 9;

        // stage input halo tile (800 floats)
        for (int i = tid; i < 800; i += 256) {
            int ci = i / 100;
            int rc = i - ci * 100;
            int r = rc / 10, c = rc - (rc / 10) * 10;
            int gh = th0 + r - 1, gw = tw0 + c - 1;
            float v = 0.0f;
            if ((unsigned)gh < (unsigned)H_ && (unsigned)gw < (unsigned)W_)
                v = comb[((b * CCOMB + ciBase + ci) * H_ + gh) * W_ + gw];
            ilds[ci][r][c] = v;
        }
        // stage weights transposed: wlds[k][oc] (9216 floats, float4 global reads)
        for (int i = tid; i < 2304; i += 256) {
            int oc = i / 18;
            int k4 = (i - oc * 18) * 4;
            const float4 v = *(const float4*)&w[(ocBase + oc) * KTOT + wkBase + k4];
            wlds[k4 + 0][oc] = v.x;
            wlds[k4 + 1][oc] = v.y;
            wlds[k4 + 2][oc] = v.z;
            wlds[k4 + 3][oc] = v.w;
        }
        __syncthreads();

        for (int ci = 0; ci < 8; ++ci) {
#pragma unroll
            for (int kh = 0; kh < 3; ++kh) {
                const float* irow = &ilds[ci][qr + kh][qc4];
#pragma unroll
                for (int kw = 0; kw < 3; ++kw) {
                    const float i0 = irow[kw + 0];
                    const float i1 = irow[kw + 1];
                    const float i2 = irow[kw + 2];
                    const float i3 = irow[kw + 3];
                    const int k = ci * 9 + kh * 3 + kw;
#pragma unroll
                    for (int o = 0; o < 8; ++o) {
                        const float wv = wlds[k][og8 + o];
                        acc[0][o] += i0 * wv;
                        acc[1][o] += i1 * wv;
                        acc[2][o] += i2 * wv;
                        acc[3][o] += i3 * wv;
                    }
                }
            }
        }
        __syncthreads();
    }

    const int h = th0 + qr;
#pragma unroll
    for (int o = 0; o < 8; ++o) {
        const int oc = ocBase + og8 + o;
        const float bv = bias[oc];
        float* dst = &cc[((b * NGATE + oc) * H_ + h) * W_ + tw0 + qc4];
#pragma unroll
        for (int j = 0; j < 4; ++j) dst[j] = acc[j][o] + bv;
    }
}

// ---------------------------------------------------------------------------
// LSTM elementwise over B*COUT*HW; writes new mem2 into comb[:, 64:192],
// spk2 to ws, and per-channel spike counts (ballot + 1 atomic per wave).
__global__ __launch_bounds__(256) void lstm_step_kernel(
        const float* __restrict__ cc, const float* __restrict__ p_th2,
        float* __restrict__ syn2, float* __restrict__ comb,
        float* __restrict__ spk2, int* __restrict__ cnt) {
#pragma clang fp contract(off)
    int i = blockIdx.x * 256 + threadIdx.x;   // 2359296 = 9216*256
    int b   = i / (COUT * HW);
    int rem = i - b * (COUT * HW);
    int c   = rem / HW;
    int p   = rem - c * HW;
    const int base = b * (NGATE * HW) + p;
    float gi = cc[base + (c            ) * HW];
    float gf = cc[base + (COUT     + c ) * HW];
    float gg = cc[base + (2 * COUT + c ) * HW];
    float go = cc[base + (3 * COUT + c ) * HW];
    float si = 1.0f / (1.0f + expf(-gi));
    float sf = 1.0f / (1.0f + expf(-gf));
    float so = 1.0f / (1.0f + expf(-go));
    float tg = tanhf(gg);
    float s2 = sf * syn2[i] + si * tg;
    float m2 = so * tanhf(s2);
    float sp = (m2 - p_th2[0]) > 0.0f ? 1.0f : 0.0f;
    syn2[i] = s2;
    comb[(b * CCOMB + CIN + c) * HW + p] = m2;
    spk2[i] = sp;
    // 2304 % 64 == 0 -> every wave lies in a single channel
    unsigned long long mask = __ballot(sp > 0.0f);
    if ((threadIdx.x & 63) == 0)
        atomicAdd(&cnt[c], (int)__popcll(mask));
}

// ---------------------------------------------------------------------------
// BN over the binary spike field: mu = cnt/NPIX (exact), var = mu - mu^2.
__global__ __launch_bounds__(256) void bn_step_kernel(
        const float* __restrict__ spk2, const int* __restrict__ cnt,
        const float* __restrict__ gamma, const float* __restrict__ bnb,
        float* __restrict__ out) {
#pragma clang fp contract(off)
    int i = blockIdx.x * 256 + threadIdx.x;
    int c = (i / HW) % COUT;
    float mu  = (float)cnt[c] / (float)NPIX;
    float var = mu - mu * mu;
    float rs  = rsqrtf(var + 1e-5f);
    float s   = spk2[i];
    out[i] = gamma[c] * (s - mu) * rs + bnb[c];
}

// ---------------------------------------------------------------------------
extern "C" void kernel_launch(void* const* d_in, const int* in_sizes, int n_in,
                              void* d_out, int out_size, void* d_ws, size_t ws_size,
                              hipStream_t stream) {
    const float* x       = (const float*)d_in[0];
    const float* p_alpha = (const float*)d_in[1];
    const float* p_beta  = (const float*)d_in[2];
    const float* p_th1   = (const float*)d_in[3];
    const float* p_th2   = (const float*)d_in[4];
    const float* w_conv  = (const float*)d_in[5];
    const float* b_conv  = (const float*)d_in[6];
    const float* gamma   = (const float*)d_in[7];
    const float* bn_beta = (const float*)d_in[8];
    float* out = (float*)d_out;

    float* wsf   = (float*)d_ws;
    float* syn_e = wsf + OFF_SYNE;
    float* syn_i = wsf + OFF_SYNI;
    float* syn2  = wsf + OFF_SYN2;
    float* comb  = wsf + OFF_COMB;
    int*   cnt   = (int*)(wsf + OFF_CNT);
    float* spk2  = wsf + OFF_SPK2;
    float* cc    = wsf + OFF_CC;

    // zero all persistent state (incl. per-timestep spike counters)
    {
        int n = ZERO_WORDS;
        zero_ws_kernel<<<(n + 255) / 256, 256, 0, stream>>>(wsf, n);
    }

    for (int t = 0; t < T_; ++t) {
        alpha_step_kernel<<<LEN_SYNE / 256, 256, 0, stream>>>(
            x + (long long)t * LEN_SYNE, p_alpha, p_beta, p_th1,
            syn_e, syn_i, comb);
        conv_gates_kernel<<<B_ * 36 * 4, 256, 0, stream>>>(
            comb, w_conv, b_conv, cc);
        lstm_step_kernel<<<LEN_SYN2 / 256, 256, 0, stream>>>(
            cc, p_th2, syn2, comb, spk2, cnt + t * COUT);
        bn_step_kernel<<<LEN_SYN2 / 256, 256, 0, stream>>>(
            spk2, cnt + t * COUT, gamma, bn_beta,
            out + (long long)t * LEN_SYN2);
    }
}

// Round 2
// 2540.971 us; speedup vs baseline: 1.1047x; 1.1047x over previous
//
#include <hip/hip_runtime.h>

// ---------------------------------------------------------------------------
// snnBlock: T=4 timesteps of
//   1) snn.Alpha      : dual-exp leaky integrator + subtract reset + spike
//   2) SConv2dLSTM    : 3x3 SAME conv (Cin+Cout=192 -> 4*Cout=512 gates), LSTM
//   3) BatchNormTT2d  : per-timestep BN over (B,H,W) of the *binary* spikes
// Shapes: x [4,8,64,48,48] f32, out [4,8,128,48,48] f32.
// ---------------------------------------------------------------------------

#define T_ 4
#define B_ 8
#define CIN 64
#define COUT 128
#define H_ 48
#define W_ 48
#define HW (H_ * W_)          // 2304
#define CCOMB (CIN + COUT)    // 192
#define NGATE (4 * COUT)      // 512
#define NPIX (B_ * HW)        // 18432
#define KTOT (CCOMB * 9)      // 1728

// ---- workspace layout (in 32-bit words) ----
#define LEN_SYNE (B_ * CIN * HW)    // 1179648
#define LEN_SYN2 (B_ * COUT * HW)   // 2359296
#define LEN_COMB (B_ * CCOMB * HW)  // 3538944
#define LEN_CC   (B_ * NGATE * HW)  // 9437184
#define LEN_CNT  (T_ * COUT)        // 512 (ints)

#define OFF_SYNE 0
#define OFF_SYNI (OFF_SYNE + LEN_SYNE)
#define OFF_SYN2 (OFF_SYNI + LEN_SYNE)
#define OFF_COMB (OFF_SYN2 + LEN_SYN2)
#define OFF_CNT  (OFF_COMB + LEN_COMB)
#define OFF_SPK2 (OFF_CNT + LEN_CNT)
#define OFF_CC   (OFF_SPK2 + LEN_SYN2)
#define ZERO_WORDS OFF_SPK2   // zero: syn_e, syn_i, syn2, comb, counts

// ---------------------------------------------------------------------------
__global__ __launch_bounds__(256) void zero_ws_kernel(float* __restrict__ p, int n) {
    int i = blockIdx.x * 256 + threadIdx.x;
    if (i < n) p[i] = 0.0f;
}

// ---------------------------------------------------------------------------
// Alpha neuron step over B*CIN*HW elements. Writes new spk1 into comb[:, 0:64].
__global__ __launch_bounds__(256) void alpha_step_kernel(
        const float* __restrict__ x_t,
        const float* __restrict__ p_alpha, const float* __restrict__ p_beta,
        const float* __restrict__ p_th1,
        float* __restrict__ syn_e, float* __restrict__ syn_i,
        float* __restrict__ comb) {
#pragma clang fp contract(off)
    int i = blockIdx.x * 256 + threadIdx.x;   // exact multiple: 1179648 = 4608*256
    float a = fminf(fmaxf(p_alpha[0], 1e-6f), 1.0f - 1e-6f);
    float b = fminf(fmaxf(p_beta[0],  1e-6f), 1.0f - 1e-6f);
    float la = logf(a), lb = logf(b);
    float tau = la / (lb - la);
    float th1 = p_th1[0];

    float xv = x_t[i];
    float e  = a * syn_e[i] + xv;
    float ii = b * syn_i[i] - xv;
    // map [b][c<64][p] -> comb [b][c][p] with comb channel stride CCOMB
    int bidx = i / (CIN * HW);
    int rem  = i - bidx * (CIN * HW);
    int cidx = bidx * (CCOMB * HW) + rem;
    float sp_prev = comb[cidx];
    float m1 = tau * (e + ii) - sp_prev * th1;
    float s1 = (m1 - th1) > 0.0f ? 1.0f : 0.0f;
    syn_e[i] = e;
    syn_i[i] = ii;
    comb[cidx] = s1;
}

// ---------------------------------------------------------------------------
// Gate conv: comb [B,192,48,48] * w [512,192,3,3] + bias -> cc [B,512,48,48]
// Block: 256 threads; one (batch, 8x8 spatial tile, 128-oc group).
// K-loop: 24 chunks of 8 input channels (72 k-elements each).
// Thread: 4 spatial (consecutive w) x 8 oc accumulators.
// Round-2 changes vs round-1:
//  * wlds row pad 129 -> 132 (16B-aligned rows) so weight reads are
//    2x ds_read_b128 per k (was 8x ds_read_b32).
//  * weight staging remapped wave-oc-sequential (conflict-free ds_write).
//  * ilds rows padded to 12 words; the 6-wide input window per (ci,kh) is
//    register-cached via one b128 + one b64 read (was 6x ds_read_b32).
#define WPAD 132
__global__ __launch_bounds__(256) void conv_gates_kernel(
        const float* __restrict__ comb, const float* __restrict__ w,
        const float* __restrict__ bias, float* __restrict__ cc) {
    __shared__ float ilds[8][10][12];     // [ci][row][col12], halo'd 8x8 tile
    __shared__ float wlds[72][WPAD];      // [k][oc]

    const int bx   = blockIdx.x;          // 0..1151
    const int ocg  = bx & 3;              // 128-oc group
    const int tile = (bx >> 2) % 36;      // 6x6 tiles of 8x8
    const int b    = bx / 144;
    const int th0  = (tile / 6) * 8;
    const int tw0  = (tile % 6) * 8;
    const int ocBase = ocg * 128;

    const int tid = threadIdx.x;
    const int q   = tid & 15;             // 16 spatial quads
    const int qr  = q >> 1;               // row 0..7
    const int qc4 = (q & 1) * 4;          // col base 0 or 4
    const int og8 = (tid >> 4) * 8;       // oc sub-base 0..120

    float acc[4][8];
#pragma unroll
    for (int j = 0; j < 4; ++j)
#pragma unroll
        for (int o = 0; o < 8; ++o) acc[j][o] = 0.0f;

    for (int cic = 0; cic < 24; ++cic) {
        const int ciBase = cic * 8;
        const int wkBase = ciBase * 9;

        // stage input halo tile (800 floats into padded rows)
        for (int i = tid; i < 800; i += 256) {
            int ci = i / 100;
            int rc = i - ci * 100;
            int r = rc / 10, c = rc - (rc / 10) * 10;
            int gh = th0 + r - 1, gw = tw0 + c - 1;
            float v = 0.0f;
            if ((unsigned)gh < (unsigned)H_ && (unsigned)gw < (unsigned)W_)
                v = comb[((b * CCOMB + ciBase + ci) * H_ + gh) * W_ + gw];
            ilds[ci][r][c] = v;
        }
        // stage weights transposed: wlds[k][oc].
        // Map: lane handles (kq = i>>7, oc = i&127) -> wave writes 64
        // consecutive ocs of one k-row quad => bank-sequential, conflict-free.
        for (int i = tid; i < 2304; i += 256) {
            int oc = i & 127;
            int kq = i >> 7;              // 0..17, k4 = kq*4
            const float4 v = *(const float4*)&w[(ocBase + oc) * KTOT + wkBase + kq * 4];
            wlds[kq * 4 + 0][oc] = v.x;
            wlds[kq * 4 + 1][oc] = v.y;
            wlds[kq * 4 + 2][oc] = v.z;
            wlds[kq * 4 + 3][oc] = v.w;
        }
        __syncthreads();

        for (int ci = 0; ci < 8; ++ci) {
#pragma unroll
            for (int kh = 0; kh < 3; ++kh) {
                // register-cache the 6-wide input window (b128 + b64)
                const float4 rA = *(const float4*)&ilds[ci][qr + kh][qc4];
                const float2 rB = *(const float2*)&ilds[ci][qr + kh][qc4 + 4];
                const float r0 = rA.x, r1 = rA.y, r2 = rA.z,
                            r3 = rA.w, r4 = rB.x, r5 = rB.y;
#pragma unroll
                for (int kw = 0; kw < 3; ++kw) {
                    const int k = ci * 9 + kh * 3 + kw;
                    const float4 w0 = *(const float4*)&wlds[k][og8];
                    const float4 w1 = *(const float4*)&wlds[k][og8 + 4];
                    const float wv[8] = {w0.x, w0.y, w0.z, w0.w,
                                         w1.x, w1.y, w1.z, w1.w};
                    const float i0 = (kw == 0) ? r0 : ((kw == 1) ? r1 : r2);
                    const float i1 = (kw == 0) ? r1 : ((kw == 1) ? r2 : r3);
                    const float i2 = (kw == 0) ? r2 : ((kw == 1) ? r3 : r4);
                    const float i3 = (kw == 0) ? r3 : ((kw == 1) ? r4 : r5);
#pragma unroll
                    for (int o = 0; o < 8; ++o) {
                        acc[0][o] += i0 * wv[o];
                        acc[1][o] += i1 * wv[o];
                        acc[2][o] += i2 * wv[o];
                        acc[3][o] += i3 * wv[o];
                    }
                }
            }
        }
        __syncthreads();
    }

    const int h = th0 + qr;
#pragma unroll
    for (int o = 0; o < 8; ++o) {
        const int oc = ocBase + og8 + o;
        const float bv = bias[oc];
        float* dst = &cc[((b * NGATE + oc) * H_ + h) * W_ + tw0 + qc4];
#pragma unroll
        for (int j = 0; j < 4; ++j) dst[j] = acc[j][o] + bv;
    }
}

// ---------------------------------------------------------------------------
// LSTM elementwise over B*COUT*HW; writes new mem2 into comb[:, 64:192],
// spk2 to ws, and per-channel spike counts (ballot + 1 atomic per wave).
__global__ __launch_bounds__(256) void lstm_step_kernel(
        const float* __restrict__ cc, const float* __restrict__ p_th2,
        float* __restrict__ syn2, float* __restrict__ comb,
        float* __restrict__ spk2, int* __restrict__ cnt) {
#pragma clang fp contract(off)
    int i = blockIdx.x * 256 + threadIdx.x;   // 2359296 = 9216*256
    int b   = i / (COUT * HW);
    int rem = i - b * (COUT * HW);
    int c   = rem / HW;
    int p   = rem - c * HW;
    const int base = b * (NGATE * HW) + p;
    float gi = cc[base + (c            ) * HW];
    float gf = cc[base + (COUT     + c ) * HW];
    float gg = cc[base + (2 * COUT + c ) * HW];
    float go = cc[base + (3 * COUT + c ) * HW];
    float si = 1.0f / (1.0f + expf(-gi));
    float sf = 1.0f / (1.0f + expf(-gf));
    float so = 1.0f / (1.0f + expf(-go));
    float tg = tanhf(gg);
    float s2 = sf * syn2[i] + si * tg;
    float m2 = so * tanhf(s2);
    float sp = (m2 - p_th2[0]) > 0.0f ? 1.0f : 0.0f;
    syn2[i] = s2;
    comb[(b * CCOMB + CIN + c) * HW + p] = m2;
    spk2[i] = sp;
    // 2304 % 64 == 0 -> every wave lies in a single channel
    unsigned long long mask = __ballot(sp > 0.0f);
    if ((threadIdx.x & 63) == 0)
        atomicAdd(&cnt[c], (int)__popcll(mask));
}

// ---------------------------------------------------------------------------
// BN over the binary spike field: mu = cnt/NPIX (exact), var = mu - mu^2.
__global__ __launch_bounds__(256) void bn_step_kernel(
        const float* __restrict__ spk2, const int* __restrict__ cnt,
        const float* __restrict__ gamma, const float* __restrict__ bnb,
        float* __restrict__ out) {
#pragma clang fp contract(off)
    int i = blockIdx.x * 256 + threadIdx.x;
    int c = (i / HW) % COUT;
    float mu  = (float)cnt[c] / (float)NPIX;
    float var = mu - mu * mu;
    float rs  = rsqrtf(var + 1e-5f);
    float s   = spk2[i];
    out[i] = gamma[c] * (s - mu) * rs + bnb[c];
}

// ---------------------------------------------------------------------------
extern "C" void kernel_launch(void* const* d_in, const int* in_sizes, int n_in,
                              void* d_out, int out_size, void* d_ws, size_t ws_size,
                              hipStream_t stream) {
    const float* x       = (const float*)d_in[0];
    const float* p_alpha = (const float*)d_in[1];
    const float* p_beta  = (const float*)d_in[2];
    const float* p_th1   = (const float*)d_in[3];
    const float* p_th2   = (const float*)d_in[4];
    const float* w_conv  = (const float*)d_in[5];
    const float* b_conv  = (const float*)d_in[6];
    const float* gamma   = (const float*)d_in[7];
    const float* bn_beta = (const float*)d_in[8];
    float* out = (float*)d_out;

    float* wsf   = (float*)d_ws;
    float* syn_e = wsf + OFF_SYNE;
    float* syn_i = wsf + OFF_SYNI;
    float* syn2  = wsf + OFF_SYN2;
    float* comb  = wsf + OFF_COMB;
    int*   cnt   = (int*)(wsf + OFF_CNT);
    float* spk2  = wsf + OFF_SPK2;
    float* cc    = wsf + OFF_CC;

    // zero all persistent state (incl. per-timestep spike counters)
    {
        int n = ZERO_WORDS;
        zero_ws_kernel<<<(n + 255) / 256, 256, 0, stream>>>(wsf, n);
    }

    for (int t = 0; t < T_; ++t) {
        alpha_step_kernel<<<LEN_SYNE / 256, 256, 0, stream>>>(
            x + (long long)t * LEN_SYNE, p_alpha, p_beta, p_th1,
            syn_e, syn_i, comb);
        conv_gates_kernel<<<B_ * 36 * 4, 256, 0, stream>>>(
            comb, w_conv, b_conv, cc);
        lstm_step_kernel<<<LEN_SYN2 / 256, 256, 0, stream>>>(
            cc, p_th2, syn2, comb, spk2, cnt + t * COUT);
        bn_step_kernel<<<LEN_SYN2 / 256, 256, 0, stream>>>(
            spk2, cnt + t * COUT, gamma, bn_beta,
            out + (long long)t * LEN_SYN2);
    }
}

// Round 3
// 1971.461 us; speedup vs baseline: 1.4239x; 1.2889x over previous
//
#include <hip/hip_runtime.h>

// ---------------------------------------------------------------------------
// snnBlock: T=4 timesteps of Alpha-neuron -> SConv2dLSTM -> per-step BN.
// x [4,8,64,48,48] f32 -> out [4,8,128,48,48] f32.
//
// Round-3 structure:
//  * t=0 is algebraic: spk1(0)=0 (x-x=0 exactly), mem2(prev)=0 => conv = bias
//    broadcast => spk2(0) per-channel uniform => BN(0) output = bn_beta.
//  * t>=1: conv fused with LSTM epilogue. Weights are wave-uniform ->
//    s_load from transposed wt[g][k][16] (scalar pipe, no LDS, no barriers).
//    Inputs staged in LDS (3.8 KB), 1 ds_read_b32 per 16 FMAs.
//  * mem2 double-buffered (conv reads prev-step mem2 while writing new).
// ---------------------------------------------------------------------------

#define T_ 4
#define B_ 8
#define CIN 64
#define COUT 128
#define H_ 48
#define W_ 48
#define HW (H_ * W_)          // 2304
#define CCOMB (CIN + COUT)    // 192
#define NGATE (4 * COUT)      // 512
#define NPIX (B_ * HW)        // 18432
#define KTOT (CCOMB * 9)      // 1728

// ---- workspace layout (32-bit words) ----
#define LEN_SYNE (B_ * CIN * HW)    // 1179648
#define LEN_SYN2 (B_ * COUT * HW)   // 2359296
#define LEN_CNT  (T_ * COUT)        // 512
#define LEN_WT   (NGATE * KTOT)     // 884736

#define OFF_SYNE 0
#define OFF_SYNI (OFF_SYNE + LEN_SYNE)
#define OFF_SPK1 (OFF_SYNI + LEN_SYNE)
#define OFF_CNT  (OFF_SPK1 + LEN_SYNE)
#define ZERO_WORDS (OFF_CNT + LEN_CNT)        // syn_e, syn_i, spk1, cnt
#define OFF_SYN2 ZERO_WORDS
#define OFF_SPK2 (OFF_SYN2 + LEN_SYN2)
#define OFF_M2A  (OFF_SPK2 + LEN_SYN2)
#define OFF_M2B  (OFF_M2A + LEN_SYN2)
#define OFF_WT   (OFF_M2B + LEN_SYN2)
#define OFF_U    (OFF_WT + LEN_WT)            // u_s2[128], u_m2[128]

// ---------------------------------------------------------------------------
__global__ __launch_bounds__(256) void zero_ws_kernel(float* __restrict__ p, int n) {
    int i = blockIdx.x * 256 + threadIdx.x;
    if (i < n) p[i] = 0.0f;
}

// ---------------------------------------------------------------------------
// wt[g][k][j]: g = ocb*4+wid (32 groups), j = gate*4 + m, cout = cb+m,
// real oc = gate*COUT + cout, cb = (g>>2)*16 + (g&3)*4.
__global__ __launch_bounds__(256) void wt_transform_kernel(
        const float* __restrict__ w, float* __restrict__ wt) {
    int id = blockIdx.x * 256 + threadIdx.x;      // g*KTOT + k, 55296 total
    int g = id / KTOT, k = id - g * KTOT;
    int cb = (g >> 2) * 16 + (g & 3) * 4;
    float* dst = wt + (size_t)id * 16;
#pragma unroll
    for (int j = 0; j < 16; ++j) {
        int gate = j >> 2, cm = cb + (j & 3);
        dst[j] = w[((gate * COUT + cm) * KTOT) + k];
    }
}

// ---------------------------------------------------------------------------
// Alpha neuron; spk1 is its own [B,64,HW] buffer now.
__global__ __launch_bounds__(256) void alpha_step_kernel(
        const float* __restrict__ x_t,
        const float* __restrict__ p_alpha, const float* __restrict__ p_beta,
        const float* __restrict__ p_th1,
        float* __restrict__ syn_e, float* __restrict__ syn_i,
        float* __restrict__ spk1) {
#pragma clang fp contract(off)
    int i = blockIdx.x * 256 + threadIdx.x;   // 1179648 = 4608*256
    float a = fminf(fmaxf(p_alpha[0], 1e-6f), 1.0f - 1e-6f);
    float b = fminf(fmaxf(p_beta[0],  1e-6f), 1.0f - 1e-6f);
    float la = logf(a), lb = logf(b);
    float tau = la / (lb - la);
    float th1 = p_th1[0];

    float xv = x_t[i];
    float e  = a * syn_e[i] + xv;
    float ii = b * syn_i[i] - xv;
    float sp_prev = spk1[i];
    float m1 = tau * (e + ii) - sp_prev * th1;
    float s1 = (m1 - th1) > 0.0f ? 1.0f : 0.0f;
    syn_e[i] = e;
    syn_i[i] = ii;
    spk1[i] = s1;
}

// ---------------------------------------------------------------------------
// t=0 per-channel LSTM-from-bias: cc = bias (conv of all-zero comb).
__global__ void t0_u_kernel(const float* __restrict__ b_conv,
                            float* __restrict__ u) {
#pragma clang fp contract(off)
    int c = threadIdx.x;                       // 128 threads
    float gi = b_conv[c], gf = b_conv[COUT + c];
    float gg = b_conv[2 * COUT + c], go = b_conv[3 * COUT + c];
    float si = 1.0f / (1.0f + expf(-gi));
    float sf = 1.0f / (1.0f + expf(-gf));
    float so = 1.0f / (1.0f + expf(-go));
    float tg = tanhf(gg);
    float s2 = sf * 0.0f + si * tg;
    float m2 = so * tanhf(s2);
    u[c] = s2;
    u[COUT + c] = m2;
}

// t=0 fill: syn2, mem2(buf A), and out(t=0) = bn_beta (BN of a per-channel
// uniform binary field is exactly bn_beta).
__global__ __launch_bounds__(256) void t0_fill_kernel(
        const float* __restrict__ u, const float* __restrict__ bnb,
        float* __restrict__ syn2, float* __restrict__ m2a,
        float* __restrict__ out0) {
    int i = blockIdx.x * 256 + threadIdx.x;    // 2359296 = 9216*256
    int c = (i / HW) % COUT;
    syn2[i] = u[c];
    m2a[i]  = u[COUT + c];
    out0[i] = bnb[c];
}

// ---------------------------------------------------------------------------
// Fused conv(3x3 SAME, 192ch -> 512 gates) + LSTM + spike + count.
// Block: 256 thr = 4 waves; wave = full 8x8 tile, 4 couts x 4 gates.
// Grid: (b 8) x (tile 36) x (ocb 8) = 2304 blocks.
__global__ __launch_bounds__(256) void conv_lstm_kernel(
        const float* __restrict__ spk1, const float* __restrict__ m2rd,
        const float* __restrict__ wt, const float* __restrict__ bias,
        const float* __restrict__ p_th2,
        float* __restrict__ syn2, float* __restrict__ m2wr,
        float* __restrict__ spk2, int* __restrict__ cnt) {
    __shared__ float ilds[8][10][12];          // halo'd 8x8 tile, 8 channels

    const int bx   = blockIdx.x;
    const int ocb  = bx & 7;
    const int tile = (bx >> 3) % 36;
    const int b    = bx / 288;
    const int th0  = (tile / 6) * 8;
    const int tw0  = (tile % 6) * 8;

    const int tid  = threadIdx.x;
    const int wid  = __builtin_amdgcn_readfirstlane(tid >> 6);
    const int lane = tid & 63;
    const int r    = lane >> 3;                // tile row 0..7
    const int c    = lane & 7;                 // tile col 0..7

    const float* __restrict__ wg = wt + (size_t)(ocb * 4 + wid) * (KTOT * 16);

    float acc[16];
#pragma unroll
    for (int j = 0; j < 16; ++j) acc[j] = 0.0f;

    for (int cic = 0; cic < 24; ++cic) {
        const int ciBase = cic * 8;
        // source: chunks 0..7 = spk1 [B,64,HW]; 8..23 = mem2 prev [B,128,HW]
        const float* csrc = (ciBase < CIN)
            ? spk1 + (size_t)(b * CIN + ciBase) * HW
            : m2rd + (size_t)(b * COUT + (ciBase - CIN)) * HW;

        __syncthreads();                       // ilds reuse guard
        for (int i = tid; i < 800; i += 256) {
            int ci = i / 100;
            int rc = i - ci * 100;
            int rr = rc / 10, cc2 = rc - (rc / 10) * 10;
            int gh = th0 + rr - 1, gw = tw0 + cc2 - 1;
            float v = 0.0f;
            if ((unsigned)gh < (unsigned)H_ && (unsigned)gw < (unsigned)W_)
                v = csrc[ci * HW + gh * W_ + gw];
            ilds[ci][rr][cc2] = v;
        }
        __syncthreads();

        const float* wchunk = wg + cic * (72 * 16);
        for (int ci = 0; ci < 8; ++ci) {
#pragma unroll
            for (int kh = 0; kh < 3; ++kh) {
                const float* wrow = wchunk + (ci * 9 + kh * 3) * 16;
                const float i0 = ilds[ci][r + kh][c + 0];
                const float i1 = ilds[ci][r + kh][c + 1];
                const float i2 = ilds[ci][r + kh][c + 2];
#pragma unroll
                for (int j = 0; j < 16; ++j) acc[j] += i0 * wrow[j];
#pragma unroll
                for (int j = 0; j < 16; ++j) acc[j] += i1 * wrow[16 + j];
#pragma unroll
                for (int j = 0; j < 16; ++j) acc[j] += i2 * wrow[32 + j];
            }
        }
    }

    // ---- fused LSTM epilogue ----
    {
#pragma clang fp contract(off)
        const float th2 = p_th2[0];
        const int cb = ocb * 16 + wid * 4;
        const int h = th0 + r, ww = tw0 + c;
#pragma unroll
        for (int m = 0; m < 4; ++m) {
            const int cm = cb + m;
            float gi = acc[m]      + bias[cm];
            float gf = acc[4 + m]  + bias[COUT + cm];
            float gg = acc[8 + m]  + bias[2 * COUT + cm];
            float go = acc[12 + m] + bias[3 * COUT + cm];
            float si = 1.0f / (1.0f + expf(-gi));
            float sf = 1.0f / (1.0f + expf(-gf));
            float so = 1.0f / (1.0f + expf(-go));
            float tg = tanhf(gg);
            const int idx = ((b * COUT + cm) * H_ + h) * W_ + ww;
            float s2 = sf * syn2[idx] + si * tg;
            float m2 = so * tanhf(s2);
            float sp = (m2 - th2) > 0.0f ? 1.0f : 0.0f;
            syn2[idx] = s2;
            m2wr[idx] = m2;
            spk2[idx] = sp;
            unsigned long long mask = __ballot(sp > 0.0f);
            if (lane == 0) atomicAdd(&cnt[cm], (int)__popcll(mask));
        }
    }
}

// ---------------------------------------------------------------------------
__global__ __launch_bounds__(256) void bn_step_kernel(
        const float* __restrict__ spk2, const int* __restrict__ cnt,
        const float* __restrict__ gamma, const float* __restrict__ bnb,
        float* __restrict__ out) {
#pragma clang fp contract(off)
    int i = blockIdx.x * 256 + threadIdx.x;
    int c = (i / HW) % COUT;
    float mu  = (float)cnt[c] / (float)NPIX;
    float var = mu - mu * mu;
    float rs  = rsqrtf(var + 1e-5f);
    float s   = spk2[i];
    out[i] = gamma[c] * (s - mu) * rs + bnb[c];
}

// ---------------------------------------------------------------------------
extern "C" void kernel_launch(void* const* d_in, const int* in_sizes, int n_in,
                              void* d_out, int out_size, void* d_ws, size_t ws_size,
                              hipStream_t stream) {
    const float* x       = (const float*)d_in[0];
    const float* p_alpha = (const float*)d_in[1];
    const float* p_beta  = (const float*)d_in[2];
    const float* p_th1   = (const float*)d_in[3];
    const float* p_th2   = (const float*)d_in[4];
    const float* w_conv  = (const float*)d_in[5];
    const float* b_conv  = (const float*)d_in[6];
    const float* gamma   = (const float*)d_in[7];
    const float* bn_beta = (const float*)d_in[8];
    float* out = (float*)d_out;

    float* wsf   = (float*)d_ws;
    float* syn_e = wsf + OFF_SYNE;
    float* syn_i = wsf + OFF_SYNI;
    float* spk1  = wsf + OFF_SPK1;
    int*   cnt   = (int*)(wsf + OFF_CNT);
    float* syn2  = wsf + OFF_SYN2;
    float* spk2  = wsf + OFF_SPK2;
    float* m2a   = wsf + OFF_M2A;
    float* m2b   = wsf + OFF_M2B;
    float* wt    = wsf + OFF_WT;
    float* u     = wsf + OFF_U;

    zero_ws_kernel<<<ZERO_WORDS / 256, 256, 0, stream>>>(wsf, ZERO_WORDS);
    wt_transform_kernel<<<(32 * KTOT) / 256, 256, 0, stream>>>(w_conv, wt);

    // ---- t = 0 (conv of all-zero comb == bias; BN of uniform == bn_beta) ----
    alpha_step_kernel<<<LEN_SYNE / 256, 256, 0, stream>>>(
        x, p_alpha, p_beta, p_th1, syn_e, syn_i, spk1);
    t0_u_kernel<<<1, COUT, 0, stream>>>(b_conv, u);
    t0_fill_kernel<<<LEN_SYN2 / 256, 256, 0, stream>>>(
        u, bn_beta, syn2, m2a, out);

    // ---- t = 1..3 ----
    float* m2buf[2] = {m2a, m2b};
    for (int t = 1; t < T_; ++t) {
        alpha_step_kernel<<<LEN_SYNE / 256, 256, 0, stream>>>(
            x + (size_t)t * LEN_SYNE, p_alpha, p_beta, p_th1,
            syn_e, syn_i, spk1);
        conv_lstm_kernel<<<2304, 256, 0, stream>>>(
            spk1, m2buf[(t - 1) & 1], wt, b_conv, p_th2,
            syn2, m2buf[t & 1], spk2, cnt + t * COUT);
        bn_step_kernel<<<LEN_SYN2 / 256, 256, 0, stream>>>(
            spk2, cnt + t * COUT, gamma, bn_beta,
            out + (size_t)t * LEN_SYN2);
    }
}

// Round 4
// 1452.963 us; speedup vs baseline: 1.9320x; 1.3569x over previous
//
#include <hip/hip_runtime.h>

// ---------------------------------------------------------------------------
// snnBlock: T=4 timesteps of Alpha-neuron -> SConv2dLSTM -> per-step BN.
// x [4,8,64,48,48] f32 -> out [4,8,128,48,48] f32.
//
// Round-4 structure (vs round-3):
//  * conv wave shape: 2 horizontally-adjacent pixels per lane (8x16 tile),
//    windows read as 2x aligned ds_read_b64 -> LDS demand ~33% of CU pipe,
//    2x s_load prefetch slack.
//  * single-barrier ping-pong LDS staging; next chunk prefetched to regs
//    under current chunk's compute.
//  * float2 fused-LSTM epilogue stores; float4 elementwise kernels.
// ---------------------------------------------------------------------------

#define T_ 4
#define B_ 8
#define CIN 64
#define COUT 128
#define H_ 48
#define W_ 48
#define HW (H_ * W_)          // 2304
#define CCOMB (CIN + COUT)    // 192
#define NGATE (4 * COUT)      // 512
#define NPIX (B_ * HW)        // 18432
#define KTOT (CCOMB * 9)      // 1728
#define WCHUNK (72 * 16)      // weight floats per chunk per 16-gch group

// ---- workspace layout (32-bit words) ----
#define LEN_SYNE (B_ * CIN * HW)    // 1179648
#define LEN_SYN2 (B_ * COUT * HW)   // 2359296
#define LEN_CNT  (T_ * COUT)        // 512
#define LEN_WT   (NGATE * KTOT)     // 884736

#define OFF_SYNE 0
#define OFF_SYNI (OFF_SYNE + LEN_SYNE)
#define OFF_SPK1 (OFF_SYNI + LEN_SYNE)
#define OFF_CNT  (OFF_SPK1 + LEN_SYNE)
#define ZERO_WORDS (OFF_CNT + LEN_CNT)        // syn_e, syn_i, spk1, cnt
#define OFF_SYN2 ZERO_WORDS
#define OFF_SPK2 (OFF_SYN2 + LEN_SYN2)
#define OFF_M2A  (OFF_SPK2 + LEN_SYN2)
#define OFF_M2B  (OFF_M2A + LEN_SYN2)
#define OFF_WT   (OFF_M2B + LEN_SYN2)
#define OFF_U    (OFF_WT + LEN_WT)            // u_s2[128], u_m2[128]

// ---------------------------------------------------------------------------
__global__ __launch_bounds__(256) void zero_ws_kernel(float* __restrict__ p, int n) {
    int i = blockIdx.x * 256 + threadIdx.x;
    if (i < n) p[i] = 0.0f;
}

// ---------------------------------------------------------------------------
// wt[g][k][j]: g = ocb*4+wid (32 groups), j = gate*4 + m, cout = cb+m,
// real oc = gate*COUT + cout, cb = (g>>2)*16 + (g&3)*4.
__global__ __launch_bounds__(256) void wt_transform_kernel(
        const float* __restrict__ w, float* __restrict__ wt) {
    int id = blockIdx.x * 256 + threadIdx.x;      // g*KTOT + k, 55296 total
    int g = id / KTOT, k = id - g * KTOT;
    int cb = (g >> 2) * 16 + (g & 3) * 4;
    float* dst = wt + (size_t)id * 16;
#pragma unroll
    for (int j = 0; j < 16; ++j) {
        int gate = j >> 2, cm = cb + (j & 3);
        dst[j] = w[((gate * COUT + cm) * KTOT) + k];
    }
}

// ---------------------------------------------------------------------------
// Alpha neuron (float4 vectorized): 294912 quads.
__global__ __launch_bounds__(256) void alpha_step_kernel(
        const float4* __restrict__ x_t,
        const float* __restrict__ p_alpha, const float* __restrict__ p_beta,
        const float* __restrict__ p_th1,
        float4* __restrict__ syn_e, float4* __restrict__ syn_i,
        float4* __restrict__ spk1) {
#pragma clang fp contract(off)
    int i = blockIdx.x * 256 + threadIdx.x;   // 294912 = 1152*256
    float a = fminf(fmaxf(p_alpha[0], 1e-6f), 1.0f - 1e-6f);
    float b = fminf(fmaxf(p_beta[0],  1e-6f), 1.0f - 1e-6f);
    float la = logf(a), lb = logf(b);
    float tau = la / (lb - la);
    float th1 = p_th1[0];

    float4 xv = x_t[i], e4 = syn_e[i], i4 = syn_i[i], s4 = spk1[i];
    float e, ii, m1;
    e = a * e4.x + xv.x; ii = b * i4.x - xv.x; m1 = tau * (e + ii) - s4.x * th1;
    e4.x = e; i4.x = ii; s4.x = (m1 - th1) > 0.0f ? 1.0f : 0.0f;
    e = a * e4.y + xv.y; ii = b * i4.y - xv.y; m1 = tau * (e + ii) - s4.y * th1;
    e4.y = e; i4.y = ii; s4.y = (m1 - th1) > 0.0f ? 1.0f : 0.0f;
    e = a * e4.z + xv.z; ii = b * i4.z - xv.z; m1 = tau * (e + ii) - s4.z * th1;
    e4.z = e; i4.z = ii; s4.z = (m1 - th1) > 0.0f ? 1.0f : 0.0f;
    e = a * e4.w + xv.w; ii = b * i4.w - xv.w; m1 = tau * (e + ii) - s4.w * th1;
    e4.w = e; i4.w = ii; s4.w = (m1 - th1) > 0.0f ? 1.0f : 0.0f;
    syn_e[i] = e4; syn_i[i] = i4; spk1[i] = s4;
}

// ---------------------------------------------------------------------------
// t=0 per-channel LSTM-from-bias: cc = bias (conv of all-zero comb).
__global__ void t0_u_kernel(const float* __restrict__ b_conv,
                            float* __restrict__ u) {
#pragma clang fp contract(off)
    int c = threadIdx.x;                       // 128 threads
    float gi = b_conv[c], gf = b_conv[COUT + c];
    float gg = b_conv[2 * COUT + c], go = b_conv[3 * COUT + c];
    float si = 1.0f / (1.0f + expf(-gi));
    float sf = 1.0f / (1.0f + expf(-gf));
    float so = 1.0f / (1.0f + expf(-go));
    float tg = tanhf(gg);
    float s2 = sf * 0.0f + si * tg;
    float m2 = so * tanhf(s2);
    u[c] = s2;
    u[COUT + c] = m2;
}

// t=0 fill: syn2, mem2(buf A), out(t=0)=bn_beta. Quad never crosses channel
// (HW divisible by 4).
__global__ __launch_bounds__(256) void t0_fill_kernel(
        const float* __restrict__ u, const float* __restrict__ bnb,
        float4* __restrict__ syn2, float4* __restrict__ m2a,
        float4* __restrict__ out0) {
    int i = blockIdx.x * 256 + threadIdx.x;    // 589824 = 2304*256
    int c = ((i * 4) / HW) % COUT;
    float s2 = u[c], m2 = u[COUT + c], bb = bnb[c];
    syn2[i] = make_float4(s2, s2, s2, s2);
    m2a[i]  = make_float4(m2, m2, m2, m2);
    out0[i] = make_float4(bb, bb, bb, bb);
}

// ---------------------------------------------------------------------------
// Fused conv(3x3 SAME, 192ch -> 512 gates) + LSTM + spike + count.
// Block: 256 thr = 4 waves; wave = 8x16 tile, 2 px/lane, 4 couts x 4 gates.
// Grid: (b 8) x (tile 18: 6 row x 3 col) x (ocb 8) = 1152 blocks.
__global__ __launch_bounds__(256) void conv_lstm_kernel(
        const float* __restrict__ spk1, const float* __restrict__ m2rd,
        const float* __restrict__ wt, const float* __restrict__ bias,
        const float* __restrict__ p_th2,
        float* __restrict__ syn2, float* __restrict__ m2wr,
        float* __restrict__ spk2, int* __restrict__ cnt) {
    __shared__ float ilds[2][8][10][20];       // ping-pong halo'd 8x16 tile

    const int bx   = blockIdx.x;
    const int ocb  = bx & 7;
    const int tile = (bx >> 3) % 18;
    const int b    = bx / 144;
    const int th0  = (tile / 3) * 8;
    const int tw0  = (tile % 3) * 16;

    const int tid  = threadIdx.x;
    const int wid  = __builtin_amdgcn_readfirstlane(tid >> 6);
    const int lane = tid & 63;
    const int r    = lane >> 3;                // tile row 0..7
    const int c2   = (lane & 7) * 2;           // output col pair base 0..14

    const float* __restrict__ wg = wt + (size_t)(ocb * 4 + wid) * (KTOT * 16);

    float acc0[16], acc1[16];
#pragma unroll
    for (int j = 0; j < 16; ++j) { acc0[j] = 0.0f; acc1[j] = 0.0f; }

    // ---- staging helpers: 1440 floats/chunk (8ci x 10rr x 18cc) ----
    float st[6];
#define LOADC(cic_)                                                          \
    {                                                                        \
        const int ciBase = (cic_) * 8;                                       \
        const float* csrc = (ciBase < CIN)                                   \
            ? spk1 + (size_t)(b * CIN + ciBase) * HW                         \
            : m2rd + (size_t)(b * COUT + (ciBase - CIN)) * HW;               \
        _Pragma("unroll")                                                    \
        for (int j = 0; j < 6; ++j) {                                        \
            int i = tid + j * 256;                                           \
            float v = 0.0f;                                                  \
            if (i < 1440) {                                                  \
                int ci = i / 180;                                            \
                int rem = i - ci * 180;                                      \
                int rr = rem / 18, cc = rem - (rem / 18) * 18;               \
                int gh = th0 + rr - 1, gw = tw0 + cc - 1;                    \
                if ((unsigned)gh < (unsigned)H_ && (unsigned)gw < (unsigned)W_) \
                    v = csrc[ci * HW + gh * W_ + gw];                        \
            }                                                                \
            st[j] = v;                                                       \
        }                                                                    \
    }
#define WRITEC(buf_)                                                         \
    {                                                                        \
        _Pragma("unroll")                                                    \
        for (int j = 0; j < 6; ++j) {                                        \
            int i = tid + j * 256;                                           \
            if (i < 1440) {                                                  \
                int ci = i / 180;                                            \
                int rem = i - ci * 180;                                      \
                int rr = rem / 18, cc = rem - (rem / 18) * 18;               \
                ilds[buf_][ci][rr][cc] = st[j];                              \
            }                                                                \
        }                                                                    \
    }

    LOADC(0);
    for (int cic = 0; cic < 24; ++cic) {
        const int buf = cic & 1;
        WRITEC(buf);
        __syncthreads();
        if (cic < 23) LOADC(cic + 1);          // prefetch under compute

        const float* wchunk = wg + cic * WCHUNK;
#pragma unroll 2
        for (int ci = 0; ci < 8; ++ci) {
#pragma unroll
            for (int kh = 0; kh < 3; ++kh) {
                const float* row = &ilds[buf][ci][r + kh][c2];
                const float2 a0 = *(const float2*)(row);
                const float2 a1 = *(const float2*)(row + 2);
                const float* wrow = wchunk + (ci * 9 + kh * 3) * 16;
#pragma unroll
                for (int j = 0; j < 16; ++j) {
                    const float wv = wrow[j];
                    acc0[j] += a0.x * wv; acc1[j] += a0.y * wv;
                }
#pragma unroll
                for (int j = 0; j < 16; ++j) {
                    const float wv = wrow[16 + j];
                    acc0[j] += a0.y * wv; acc1[j] += a1.x * wv;
                }
#pragma unroll
                for (int j = 0; j < 16; ++j) {
                    const float wv = wrow[32 + j];
                    acc0[j] += a1.x * wv; acc1[j] += a1.y * wv;
                }
            }
        }
        // no trailing barrier needed: next WRITEC targets the other buffer,
        // and the loop-top barrier orders it against all older reads.
    }

    // ---- fused LSTM epilogue (2 pixels via float2) ----
    {
#pragma clang fp contract(off)
        const float th2 = p_th2[0];
        const int cb = ocb * 16 + wid * 4;
        const int h = th0 + r, ww = tw0 + c2;
#pragma unroll
        for (int m = 0; m < 4; ++m) {
            const int cm = cb + m;
            const float b0 = bias[cm],            b1 = bias[COUT + cm];
            const float b2 = bias[2 * COUT + cm], b3 = bias[3 * COUT + cm];
            const int idx = ((b * COUT + cm) * H_ + h) * W_ + ww;
            const float2 s2old = *(const float2*)&syn2[idx];
            float2 s2n, m2n, spn;
            {
                float gi = acc0[m] + b0, gf = acc0[4 + m] + b1;
                float gg = acc0[8 + m] + b2, go = acc0[12 + m] + b3;
                float si = 1.0f / (1.0f + expf(-gi));
                float sf = 1.0f / (1.0f + expf(-gf));
                float so = 1.0f / (1.0f + expf(-go));
                float tg = tanhf(gg);
                float s2 = sf * s2old.x + si * tg;
                float m2 = so * tanhf(s2);
                s2n.x = s2; m2n.x = m2;
                spn.x = (m2 - th2) > 0.0f ? 1.0f : 0.0f;
            }
            {
                float gi = acc1[m] + b0, gf = acc1[4 + m] + b1;
                float gg = acc1[8 + m] + b2, go = acc1[12 + m] + b3;
                float si = 1.0f / (1.0f + expf(-gi));
                float sf = 1.0f / (1.0f + expf(-gf));
                float so = 1.0f / (1.0f + expf(-go));
                float tg = tanhf(gg);
                float s2 = sf * s2old.y + si * tg;
                float m2 = so * tanhf(s2);
                s2n.y = s2; m2n.y = m2;
                spn.y = (m2 - th2) > 0.0f ? 1.0f : 0.0f;
            }
            *(float2*)&syn2[idx] = s2n;
            *(float2*)&m2wr[idx] = m2n;
            *(float2*)&spk2[idx] = spn;
            unsigned long long mk0 = __ballot(spn.x > 0.0f);
            unsigned long long mk1 = __ballot(spn.y > 0.0f);
            if (lane == 0)
                atomicAdd(&cnt[cm], (int)(__popcll(mk0) + __popcll(mk1)));
        }
    }
#undef LOADC
#undef WRITEC
}

// ---------------------------------------------------------------------------
// BN of the binary spike field (float4): mu = cnt/NPIX exact, var = mu - mu^2.
__global__ __launch_bounds__(256) void bn_step_kernel(
        const float4* __restrict__ spk2, const int* __restrict__ cnt,
        const float* __restrict__ gamma, const float* __restrict__ bnb,
        float4* __restrict__ out) {
#pragma clang fp contract(off)
    int i = blockIdx.x * 256 + threadIdx.x;    // 589824 = 2304*256
    int c = ((i * 4) / HW) % COUT;
    float mu  = (float)cnt[c] / (float)NPIX;
    float var = mu - mu * mu;
    float rs  = rsqrtf(var + 1e-5f);
    float g = gamma[c], bb = bnb[c];
    float4 s = spk2[i];
    out[i] = make_float4(g * (s.x - mu) * rs + bb, g * (s.y - mu) * rs + bb,
                         g * (s.z - mu) * rs + bb, g * (s.w - mu) * rs + bb);
}

// ---------------------------------------------------------------------------
extern "C" void kernel_launch(void* const* d_in, const int* in_sizes, int n_in,
                              void* d_out, int out_size, void* d_ws, size_t ws_size,
                              hipStream_t stream) {
    const float* x       = (const float*)d_in[0];
    const float* p_alpha = (const float*)d_in[1];
    const float* p_beta  = (const float*)d_in[2];
    const float* p_th1   = (const float*)d_in[3];
    const float* p_th2   = (const float*)d_in[4];
    const float* w_conv  = (const float*)d_in[5];
    const float* b_conv  = (const float*)d_in[6];
    const float* gamma   = (const float*)d_in[7];
    const float* bn_beta = (const float*)d_in[8];
    float* out = (float*)d_out;

    float* wsf   = (float*)d_ws;
    float* syn_e = wsf + OFF_SYNE;
    float* syn_i = wsf + OFF_SYNI;
    float* spk1  = wsf + OFF_SPK1;
    int*   cnt   = (int*)(wsf + OFF_CNT);
    float* syn2  = wsf + OFF_SYN2;
    float* spk2  = wsf + OFF_SPK2;
    float* m2a   = wsf + OFF_M2A;
    float* m2b   = wsf + OFF_M2B;
    float* wt    = wsf + OFF_WT;
    float* u     = wsf + OFF_U;

    zero_ws_kernel<<<(ZERO_WORDS + 255) / 256, 256, 0, stream>>>(wsf, ZERO_WORDS);
    wt_transform_kernel<<<(32 * KTOT) / 256, 256, 0, stream>>>(w_conv, wt);

    // ---- t = 0 (conv of all-zero comb == bias; BN of uniform == bn_beta) ----
    alpha_step_kernel<<<LEN_SYNE / 1024, 256, 0, stream>>>(
        (const float4*)x, p_alpha, p_beta, p_th1,
        (float4*)syn_e, (float4*)syn_i, (float4*)spk1);
    t0_u_kernel<<<1, COUT, 0, stream>>>(b_conv, u);
    t0_fill_kernel<<<LEN_SYN2 / 1024, 256, 0, stream>>>(
        u, bn_beta, (float4*)syn2, (float4*)m2a, (float4*)out);

    // ---- t = 1..3 ----
    float* m2buf[2] = {m2a, m2b};
    for (int t = 1; t < T_; ++t) {
        alpha_step_kernel<<<LEN_SYNE / 1024, 256, 0, stream>>>(
            (const float4*)(x + (size_t)t * LEN_SYNE), p_alpha, p_beta, p_th1,
            (float4*)syn_e, (float4*)syn_i, (float4*)spk1);
        conv_lstm_kernel<<<1152, 256, 0, stream>>>(
            spk1, m2buf[(t - 1) & 1], wt, b_conv, p_th2,
            syn2, m2buf[t & 1], spk2, cnt + t * COUT);
        bn_step_kernel<<<LEN_SYN2 / 1024, 256, 0, stream>>>(
            (const float4*)spk2, cnt + t * COUT, gamma, bn_beta,
            (float4*)(out + (size_t)t * LEN_SYN2));
    }
}